// Round 1
// baseline (186.102 us; speedup 1.0000x reference)
//
#include <hip/hip_runtime.h>
#include <hip/hip_bf16.h>

// Problem: out[b,c] = exp(-GAMMA * (||x_b||^2 + ||c_c||^2 - 2 x_b.c_c))
// B = 4096 rows of x, C = 4096 centers, D = 2048. fp32 in, fp32 out.
// Strategy: cast to bf16 in workspace + fp32 row norms (prep kernel),
// then m97-style 128x128-tile MFMA GEMM (16x16x32 bf16) with fused exp epilogue.
// Workspace use: 2*4096*2048*2 B (bf16 copies) + 2*4096*4 B (norms) = 33.6 MB.

#define B_DIM 4096
#define C_DIM 4096
#define D_DIM 2048
#define GAMMA 0.05f

typedef __bf16 bf16_t;
typedef bf16_t bf16x8 __attribute__((ext_vector_type(8)));
typedef float floatx4 __attribute__((ext_vector_type(4)));

__device__ inline void async_load16(const void* gptr, void* lptr) {
    // global -> LDS direct copy, 16B per lane. LDS dest is wave-uniform base
    // + lane*16; our lds pointers are computed exactly that way.
    __builtin_amdgcn_global_load_lds((const __attribute__((address_space(1))) void*)gptr,
                                     (__attribute__((address_space(3))) void*)lptr,
                                     16, 0, 0);
}

// One block per row: cast 2048 fp32 -> bf16 and compute sum of squares (fp32).
__global__ void prep_cast(const float* __restrict__ src, bf16_t* __restrict__ dst,
                          float* __restrict__ sq)
{
    const int row = blockIdx.x;
    const int t   = threadIdx.x;              // 256 threads
    const float4* s = (const float4*)(src + (size_t)row * D_DIM);
    float4 v0 = s[t * 2 + 0];
    float4 v1 = s[t * 2 + 1];
    float ss = v0.x*v0.x + v0.y*v0.y + v0.z*v0.z + v0.w*v0.w
             + v1.x*v1.x + v1.y*v1.y + v1.z*v1.z + v1.w*v1.w;

    bf16x8 o;
    o[0] = (bf16_t)v0.x; o[1] = (bf16_t)v0.y; o[2] = (bf16_t)v0.z; o[3] = (bf16_t)v0.w;
    o[4] = (bf16_t)v1.x; o[5] = (bf16_t)v1.y; o[6] = (bf16_t)v1.z; o[7] = (bf16_t)v1.w;
    *(bf16x8*)(dst + (size_t)row * D_DIM + t * 8) = o;

    // wave (64-lane) reduction, then cross-wave via LDS
    for (int off = 32; off > 0; off >>= 1) ss += __shfl_down(ss, off, 64);
    __shared__ float wsum[4];
    if ((t & 63) == 0) wsum[t >> 6] = ss;
    __syncthreads();
    if (t == 0) sq[row] = wsum[0] + wsum[1] + wsum[2] + wsum[3];
}

// 128x128 output tile per block, 256 threads = 4 waves in 2x2, each wave owns
// a 64x64 region = 4x4 grid of 16x16x32 MFMA tiles. BK = 32.
__global__ void rbf_gemm(const bf16_t* __restrict__ xb, const bf16_t* __restrict__ cb,
                         const float* __restrict__ xsq, const float* __restrict__ csq,
                         float* __restrict__ out)
{
    __shared__ __align__(16) bf16_t As[128 * 32];  // 8 KB, row-major [128][32]
    __shared__ __align__(16) bf16_t Bs[128 * 32];  // 8 KB

    const int t    = threadIdx.x;
    const int lane = t & 63;
    const int wave = t >> 6;
    const int wm   = wave & 1;         // wave row (0..1)
    const int wn   = wave >> 1;        // wave col (0..1)
    const int row0 = blockIdx.x * 128; // x rows
    const int col0 = blockIdx.y * 128; // center rows (= out cols)

    const int quad = lane >> 4;
    const int l15  = lane & 15;

    floatx4 acc[4][4];
#pragma unroll
    for (int i = 0; i < 4; i++)
#pragma unroll
        for (int j = 0; j < 4; j++)
            acc[i][j] = (floatx4){0.f, 0.f, 0.f, 0.f};

    // Staging: 128x32 bf16 tile = 8192 B = 512 x 16B slots; 256 threads x 2.
    // slot -> row = slot>>2, 8-elem group = slot&3. LDS byte off = slot*16.
    const int s0 = t;
    const int s1 = t + 256;
    const size_t aoff0 = (size_t)(row0 + (s0 >> 2)) * D_DIM + (s0 & 3) * 8;
    const size_t aoff1 = (size_t)(row0 + (s1 >> 2)) * D_DIM + (s1 & 3) * 8;
    const size_t boff0 = (size_t)(col0 + (s0 >> 2)) * D_DIM + (s0 & 3) * 8;
    const size_t boff1 = (size_t)(col0 + (s1 >> 2)) * D_DIM + (s1 & 3) * 8;

    for (int k0 = 0; k0 < D_DIM; k0 += 32) {
        __syncthreads();  // previous tile's compute done before overwrite
        async_load16(xb + aoff0 + k0, &As[s0 * 8]);
        async_load16(xb + aoff1 + k0, &As[s1 * 8]);
        async_load16(cb + boff0 + k0, &Bs[s0 * 8]);
        async_load16(cb + boff1 + k0, &Bs[s1 * 8]);
        __syncthreads();  // implies s_waitcnt vmcnt(0): tiles visible

        bf16x8 a[4], b[4];
#pragma unroll
        for (int i = 0; i < 4; i++) {
            const int r = wm * 64 + i * 16 + l15;     // A fragment: m = lane&15
            a[i] = *(const bf16x8*)&As[r * 32 + quad * 8];
        }
#pragma unroll
        for (int j = 0; j < 4; j++) {
            const int c = wn * 64 + j * 16 + l15;     // B fragment: n = lane&15
            b[j] = *(const bf16x8*)&Bs[c * 32 + quad * 8];
        }
#pragma unroll
        for (int i = 0; i < 4; i++)
#pragma unroll
            for (int j = 0; j < 4; j++)
                acc[i][j] = __builtin_amdgcn_mfma_f32_16x16x32_bf16(a[i], b[j], acc[i][j], 0, 0, 0);
    }

    // Epilogue: C/D layout col = lane&15, row = (lane>>4)*4 + reg.
#pragma unroll
    for (int i = 0; i < 4; i++) {
        const int r0 = row0 + wm * 64 + i * 16 + quad * 4;
#pragma unroll
        for (int j = 0; j < 4; j++) {
            const int c  = col0 + wn * 64 + j * 16 + l15;
            const float cs = csq[c];
#pragma unroll
            for (int reg = 0; reg < 4; reg++) {
                const int r = r0 + reg;
                const float dist = xsq[r] + cs - 2.0f * acc[i][j][reg];
                out[(size_t)r * C_DIM + c] = __expf(-GAMMA * dist);
            }
        }
    }
}

extern "C" void kernel_launch(void* const* d_in, const int* in_sizes, int n_in,
                              void* d_out, int out_size, void* d_ws, size_t ws_size,
                              hipStream_t stream)
{
    const float* x       = (const float*)d_in[0];
    const float* centers = (const float*)d_in[1];
    float* out = (float*)d_out;

    char* ws = (char*)d_ws;
    bf16_t* xb  = (bf16_t*)ws;
    bf16_t* cb  = (bf16_t*)(ws + (size_t)B_DIM * D_DIM * 2);
    float*  xsq = (float*)(ws + (size_t)(B_DIM + C_DIM) * D_DIM * 2);
    float*  csq = xsq + B_DIM;

    prep_cast<<<B_DIM, 256, 0, stream>>>(x, xb, xsq);
    prep_cast<<<C_DIM, 256, 0, stream>>>(centers, cb, csq);
    rbf_gemm<<<dim3(B_DIM / 128, C_DIM / 128), 256, 0, stream>>>(xb, cb, xsq, csq, out);
}